// Round 12
// baseline (191.631 us; speedup 1.0000x reference)
//
#include <hip/hip_runtime.h>

typedef _Float16 half8 __attribute__((ext_vector_type(8)));
typedef _Float16 half4 __attribute__((ext_vector_type(4)));
typedef float f32x4 __attribute__((ext_vector_type(4)));

constexpr int B = 2, L = 2048, S = 2048, H = 16, E = 64, D = 64;
constexpr int BM = 64;   // Q rows per workgroup: 2 waves x 32 rows (round-3 per-wave shape)
constexpr int BN = 64;   // K/V rows per iteration
constexpr int LDT = 72;  // f16 leading dim: 36-dword rows, 16B-aligned
constexpr int NTI = S / BN;

__global__ __launch_bounds__(128, 2)
void fa_kernel(const float* __restrict__ Qg, const float* __restrict__ Kg,
               const float* __restrict__ Vg, const float* __restrict__ Mg,
               float* __restrict__ Og)
{
    __shared__ _Float16 sK[BN][LDT];     // K tile [s][e]
    __shared__ _Float16 sV[D][LDT];      // V^T [d][s]; 16B chunk swizzle: phys = cl ^ ((d>>3)&7)
    __shared__ _Float16 sP[2][32][LDT];  // per-wave P [qrow 0..31][s]

    const int tid  = threadIdx.x;
    const int wave = tid >> 6;     // 0..1
    const int lane = tid & 63;
    const int quad = lane >> 4;
    const int lq   = lane & 15;

    // XCD-aware decode: WG i lands on XCD i%8; each XCD owns 4 (b,h) -> K/V set = 4 MB = L2.
    const int i  = blockIdx.x;             // grid = 1024 -> 4 WGs/CU
    const int bh = (i & 7) * 4 + ((i >> 3) & 3);
    const int qb = i >> 5;                 // 0..31
    const int b  = bh >> 4;
    const int h  = bh & 15;
    const int q0 = qb * BM;

    const int rowStride = H * E;  // 1024 floats
    const size_t qbase = ((size_t)b * L) * rowStride + h * E;
    const size_t kbase = ((size_t)b * S) * rowStride + h * E;

    const float cS = 0.125f * 1.44269504089f;  // scale*log2(e); fixed-shift exp2 softmax

    // ---- Q fragments for 2 q-groups, prescaled (B-operand: n=q=lq, k=e=ks*32+quad*8+j) ----
    half8 qf[2][2];
    #pragma unroll
    for (int g = 0; g < 2; ++g) {
        const float* qp = Qg + qbase + (size_t)(q0 + wave*32 + g*16 + lq) * rowStride + quad*8;
        #pragma unroll
        for (int ks = 0; ks < 2; ++ks)
            #pragma unroll
            for (int j = 0; j < 8; ++j)
                qf[g][ks][j] = (_Float16)(qp[ks*32 + j] * cS);
    }

    const float* mrow0 = Mg + (size_t)(q0 + wave*32 + lq) * S;  // g offset: +16*S

    float lsum[2] = {0.f, 0.f};
    f32x4 oacc[2][4];
    #pragma unroll
    for (int g = 0; g < 2; ++g)
        #pragma unroll
        for (int dt = 0; dt < 4; ++dt) oacc[g][dt] = (f32x4){0.f, 0.f, 0.f, 0.f};

    // staging decompositions (128 threads stage the 64x64 K and V tiles; 2x rows/thread)
    const int db = tid & 15;       // d-quad for V transpose
    const int sb = tid >> 4;       // 0..7: 8 s-rows each
    const float* vbase = Vg + kbase + (size_t)(sb*8) * rowStride + db*4;
    const float* krow  = Kg + kbase + (size_t)(tid >> 4) * rowStride + (tid & 15)*4;  // K row base 0..7

    // async-STAGE pipeline regs: tile t+1 lives here while tile t computes
    float4 kreg[8], vreg[8], mreg[2][4];

    // ---- prologue: load + stage tile 0, prefetch mask tile 0 ----
    #pragma unroll
    for (int ii = 0; ii < 8; ++ii)
        kreg[ii] = *(const float4*)(krow + (size_t)(ii*8) * rowStride);
    #pragma unroll
    for (int j = 0; j < 8; ++j)
        vreg[j] = *(const float4*)(vbase + (size_t)j * rowStride);
    #pragma unroll
    for (int g = 0; g < 2; ++g)
        #pragma unroll
        for (int nt = 0; nt < 4; ++nt)
            mreg[g][nt] = *(const float4*)(mrow0 + (size_t)g*16*S + nt*16 + quad*4);

    #pragma unroll
    for (int ii = 0; ii < 8; ++ii) {
        half4 hk = {(_Float16)kreg[ii].x, (_Float16)kreg[ii].y,
                    (_Float16)kreg[ii].z, (_Float16)kreg[ii].w};
        *(half4*)&sK[(tid >> 4) + ii*8][(tid & 15)*4] = hk;
    }
    // V transpose writes: logical s-chunk cl = sb of row d, phys = cl ^ ((d>>3)&7);
    // d = db*4+jj -> (d>>3)&7 == db>>1. Two s-halves k=0,1 at +k*4 within the chunk.
    #pragma unroll
    for (int jj = 0; jj < 4; ++jj)
        #pragma unroll
        for (int k = 0; k < 2; ++k) {
            half4 hv = { (_Float16)((&vreg[k*4+0].x)[jj]), (_Float16)((&vreg[k*4+1].x)[jj]),
                         (_Float16)((&vreg[k*4+2].x)[jj]), (_Float16)((&vreg[k*4+3].x)[jj]) };
            *(half4*)&sV[db*4 + jj][((sb ^ (db >> 1)) << 3) + (k << 2)] = hv;
        }
    __syncthreads();

    for (int t = 0; t < NTI; ++t) {
        // ---- prefetch K/V tile t+1 into regs: latency hides under this tile's compute ----
        if (t + 1 < NTI) {
            const int s1 = (t + 1) * BN;
            #pragma unroll
            for (int ii = 0; ii < 8; ++ii)
                kreg[ii] = *(const float4*)(krow + (size_t)(s1 + ii*8) * rowStride);
            #pragma unroll
            for (int j = 0; j < 8; ++j)
                vreg[j] = *(const float4*)(vbase + (size_t)(s1 + j) * rowStride);
        }

        // ---- S^T = K Q^T (C: row=s, col=q=lq); each K-frag feeds BOTH q-groups ----
        f32x4 sf[2][4];
        __builtin_amdgcn_s_setprio(1);
        #pragma unroll
        for (int nt = 0; nt < 4; ++nt) {
            half8 kf0 = *(const half8*)&sK[nt*16 + lq][ 0 + quad*8];
            half8 kf1 = *(const half8*)&sK[nt*16 + lq][32 + quad*8];
            #pragma unroll
            for (int g = 0; g < 2; ++g) {
                f32x4 acc = (f32x4){0.f, 0.f, 0.f, 0.f};
                acc = __builtin_amdgcn_mfma_f32_16x16x32_f16(kf0, qf[g][0], acc, 0, 0, 0);
                acc = __builtin_amdgcn_mfma_f32_16x16x32_f16(kf1, qf[g][1], acc, 0, 0, 0);
                sf[g][nt] = acc;
            }
        }
        __builtin_amdgcn_s_setprio(0);

        // ---- p = exp2(logit + mask*cS); accumulate l; packed b64 stores to sP ----
        #pragma unroll
        for (int g = 0; g < 2; ++g)
            #pragma unroll
            for (int nt = 0; nt < 4; ++nt) {
                half4 hp;
                #pragma unroll
                for (int r = 0; r < 4; ++r) {
                    float lg = fmaf((&mreg[g][nt].x)[r], cS, sf[g][nt][r]);
                    float p  = __builtin_amdgcn_exp2f(lg);
                    lsum[g] += p;
                    hp[r] = (_Float16)p;
                }
                *(half4*)&sP[wave][g*16 + lq][nt*16 + quad*4] = hp;
            }

        // ---- prefetch mask tile t+1 (L3-resident): hides under PV + staging ----
        if (t + 1 < NTI) {
            const int s1 = (t + 1) * BN;
            #pragma unroll
            for (int g = 0; g < 2; ++g)
                #pragma unroll
                for (int nt = 0; nt < 4; ++nt)
                    mreg[g][nt] = *(const float4*)(mrow0 + (size_t)g*16*S + s1 + nt*16 + quad*4);
        }

        // ---- O += P V : each V-frag feeds BOTH q-groups ----
        __builtin_amdgcn_s_setprio(1);
        #pragma unroll
        for (int ks = 0; ks < 2; ++ks) {
            half8 pf0 = *(const half8*)&sP[wave][ 0 + lq][ks*32 + quad*8];
            half8 pf1 = *(const half8*)&sP[wave][16 + lq][ks*32 + quad*8];
            #pragma unroll
            for (int dt = 0; dt < 4; ++dt) {
                const int vrow = dt*16 + lq;
                const int phys = (ks*4 + quad) ^ ((vrow >> 3) & 7);
                half8 vf = *(const half8*)&sV[vrow][phys << 3];
                oacc[0][dt] = __builtin_amdgcn_mfma_f32_16x16x32_f16(pf0, vf, oacc[0][dt], 0, 0, 0);
                oacc[1][dt] = __builtin_amdgcn_mfma_f32_16x16x32_f16(pf1, vf, oacc[1][dt], 0, 0, 0);
            }
        }
        __builtin_amdgcn_s_setprio(0);

        // ---- write-late: convert prefetched regs -> LDS for tile t+1 ----
        if (t + 1 < NTI) {
            __syncthreads();   // B2: all sK/sV reads for tile t done
            #pragma unroll
            for (int ii = 0; ii < 8; ++ii) {
                half4 hk = {(_Float16)kreg[ii].x, (_Float16)kreg[ii].y,
                            (_Float16)kreg[ii].z, (_Float16)kreg[ii].w};
                *(half4*)&sK[(tid >> 4) + ii*8][(tid & 15)*4] = hk;
            }
            #pragma unroll
            for (int jj = 0; jj < 4; ++jj)
                #pragma unroll
                for (int k = 0; k < 2; ++k) {
                    half4 hv = { (_Float16)((&vreg[k*4+0].x)[jj]), (_Float16)((&vreg[k*4+1].x)[jj]),
                                 (_Float16)((&vreg[k*4+2].x)[jj]), (_Float16)((&vreg[k*4+3].x)[jj]) };
                    *(half4*)&sV[db*4 + jj][((sb ^ (db >> 1)) << 3) + (k << 2)] = hv;
                }
            __syncthreads();   // B1: tile t+1 staged and visible
        }
    }

    // ---- epilogue per q-group: l reduction across quads, O /= l, store fp32 ----
    #pragma unroll
    for (int g = 0; g < 2; ++g) {
        float l = lsum[g];
        l += __shfl_xor(l, 16);
        l += __shfl_xor(l, 32);
        #pragma unroll
        for (int r = 0; r < 4; ++r) {
            float l_bc = __shfl(l, quad*4 + r, 16);
            float inv = 1.f / l_bc;
            float* orow = Og + qbase + (size_t)(q0 + wave*32 + g*16 + quad*4 + r) * rowStride;
            #pragma unroll
            for (int dt = 0; dt < 4; ++dt)
                orow[dt*16 + lq] = oacc[g][dt][r] * inv;
        }
    }
}

extern "C" void kernel_launch(void* const* d_in, const int* in_sizes, int n_in,
                              void* d_out, int out_size, void* d_ws, size_t ws_size,
                              hipStream_t stream) {
    const float* Qg = (const float*)d_in[0];
    const float* Kg = (const float*)d_in[1];
    const float* Vg = (const float*)d_in[2];
    const float* Mg = (const float*)d_in[3];
    float* Og = (float*)d_out;
    dim3 grid((L / BM) * B * H);   // 1024 WGs = 4 per CU
    fa_kernel<<<grid, 128, 0, stream>>>(Qg, Kg, Vg, Mg, Og);
}

// Round 13
// 176.024 us; speedup vs baseline: 1.0887x; 1.0887x over previous
//
#include <hip/hip_runtime.h>

typedef _Float16 half8 __attribute__((ext_vector_type(8)));
typedef _Float16 half4 __attribute__((ext_vector_type(4)));
typedef float f32x4 __attribute__((ext_vector_type(4)));

constexpr int B = 2, L = 2048, S = 2048, H = 16, E = 64, D = 64;
constexpr int BM = 128;  // Q rows per workgroup (32 per wave: 2x MFMA per LDS read)
constexpr int BN = 64;   // K/V rows per iteration
constexpr int LDT = 72;  // f16 leading dim: 36-dword rows, 16B-aligned
constexpr int NTI = S / BN;

// One K/V step on buffer BUF; stages tile T+1 into BUF^1 (overlapped with
// compute -- different buffer), then a SINGLE __syncthreads per iteration.
#define TILE_STEP(BUF, MC, MN, T)                                                           \
{                                                                                           \
    /* prefetch K/V tile T+1 into regs (latency hides under compute) */                     \
    if ((T) + 1 < NTI) {                                                                    \
        const int s1 = ((T) + 1) * BN;                                                      \
        _Pragma("unroll")                                                                   \
        for (int ii = 0; ii < 4; ++ii)                                                      \
            kreg[ii] = *(const float4*)(krow + (size_t)(s1 + ii*16) * rowStride);           \
        _Pragma("unroll")                                                                   \
        for (int j = 0; j < 4; ++j)                                                         \
            vreg[j] = *(const float4*)(vbase + (size_t)(s1 + j) * rowStride);               \
    }                                                                                       \
    /* S^T = K Q^T (C: row=s, col=q=lq); each K-frag feeds BOTH q-groups */                 \
    f32x4 sf[2][4];                                                                         \
    __builtin_amdgcn_s_setprio(1);                                                          \
    _Pragma("unroll")                                                                       \
    for (int nt = 0; nt < 4; ++nt) {                                                        \
        half8 kf0 = *(const half8*)&sK[BUF][nt*16 + lq][ 0 + quad*8];                       \
        half8 kf1 = *(const half8*)&sK[BUF][nt*16 + lq][32 + quad*8];                       \
        _Pragma("unroll")                                                                   \
        for (int g = 0; g < 2; ++g) {                                                       \
            f32x4 acc = (f32x4){0.f, 0.f, 0.f, 0.f};                                        \
            acc = __builtin_amdgcn_mfma_f32_16x16x32_f16(kf0, qf[g][0], acc, 0, 0, 0);      \
            acc = __builtin_amdgcn_mfma_f32_16x16x32_f16(kf1, qf[g][1], acc, 0, 0, 0);      \
            sf[g][nt] = acc;                                                                \
        }                                                                                   \
    }                                                                                       \
    __builtin_amdgcn_s_setprio(0);                                                          \
    /* p = exp2(logit + mask*cS); accumulate l; packed b64 stores to sP */                  \
    _Pragma("unroll")                                                                       \
    for (int g = 0; g < 2; ++g)                                                             \
        _Pragma("unroll")                                                                   \
        for (int nt = 0; nt < 4; ++nt) {                                                    \
            half4 hp;                                                                       \
            _Pragma("unroll")                                                               \
            for (int r = 0; r < 4; ++r) {                                                   \
                float lg = fmaf((&MC[g][nt].x)[r], cS, sf[g][nt][r]);                       \
                float p  = __builtin_amdgcn_exp2f(lg);                                      \
                lsum[g] += p;                                                               \
                hp[r] = (_Float16)p;                                                        \
            }                                                                               \
            *(half4*)&sP[wave][g*16 + lq][nt*16 + quad*4] = hp;                             \
        }                                                                                   \
    /* prefetch mask tile T+1 (L3-resident) */                                              \
    if ((T) + 1 < NTI) {                                                                    \
        const int s1 = ((T) + 1) * BN;                                                      \
        _Pragma("unroll")                                                                   \
        for (int g = 0; g < 2; ++g)                                                         \
            _Pragma("unroll")                                                               \
            for (int nt = 0; nt < 4; ++nt)                                                  \
                MN[g][nt] = *(const float4*)(mrow0 + (size_t)g*16*S + s1 + nt*16 + quad*4); \
    }                                                                                       \
    /* O += P V : each V-frag feeds BOTH q-groups */                                        \
    __builtin_amdgcn_s_setprio(1);                                                          \
    _Pragma("unroll")                                                                       \
    for (int ks = 0; ks < 2; ++ks) {                                                        \
        half8 pf0 = *(const half8*)&sP[wave][ 0 + lq][ks*32 + quad*8];                      \
        half8 pf1 = *(const half8*)&sP[wave][16 + lq][ks*32 + quad*8];                      \
        _Pragma("unroll")                                                                   \
        for (int dt = 0; dt < 4; ++dt) {                                                    \
            const int vrow = dt*16 + lq;                                                    \
            const int phys = (ks*4 + quad) ^ ((vrow >> 3) & 7);                             \
            half8 vf = *(const half8*)&sV[BUF][vrow][phys << 3];                            \
            oacc[0][dt] = __builtin_amdgcn_mfma_f32_16x16x32_f16(pf0, vf, oacc[0][dt],0,0,0);\
            oacc[1][dt] = __builtin_amdgcn_mfma_f32_16x16x32_f16(pf1, vf, oacc[1][dt],0,0,0);\
        }                                                                                   \
    }                                                                                       \
    __builtin_amdgcn_s_setprio(0);                                                          \
    /* write tile T+1 into the OTHER buffer (overlaps: no barrier before) */                \
    if ((T) + 1 < NTI) {                                                                    \
        _Pragma("unroll")                                                                   \
        for (int ii = 0; ii < 4; ++ii) {                                                    \
            half4 hk = {(_Float16)kreg[ii].x, (_Float16)kreg[ii].y,                         \
                        (_Float16)kreg[ii].z, (_Float16)kreg[ii].w};                        \
            *(half4*)&sK[(BUF) ^ 1][(tid >> 4) + ii*16][(tid & 15)*4] = hk;                 \
        }                                                                                   \
        _Pragma("unroll")                                                                   \
        for (int j = 0; j < 4; ++j) {                                                       \
            half4 hv = { (_Float16)((&kvx(0))[j]), (_Float16)((&kvx(1))[j]),                \
                         (_Float16)((&kvx(2))[j]), (_Float16)((&kvx(3))[j]) };              \
            *(half4*)&sV[(BUF) ^ 1][db*4 + j][voff] = hv;                                   \
        }                                                                                   \
        __syncthreads();  /* writes to BUF^1 visible; reads of BUF done before next overwrite */\
    }                                                                                       \
}

#define kvx(n) vreg[n].x

__global__ __launch_bounds__(256, 2)
void fa_kernel(const float* __restrict__ Qg, const float* __restrict__ Kg,
               const float* __restrict__ Vg, const float* __restrict__ Mg,
               float* __restrict__ Og)
{
    __shared__ _Float16 sK[2][BN][LDT];  // K tiles [s][e], double-buffered
    __shared__ _Float16 sV[2][D][LDT];   // V^T [d][s]; 16B chunk swizzle: phys = cl ^ ((d>>3)&7)
    __shared__ _Float16 sP[4][32][LDT];  // per-wave P [qrow 0..31][s]

    const int tid  = threadIdx.x;
    const int wave = tid >> 6;
    const int lane = tid & 63;
    const int quad = lane >> 4;
    const int lq   = lane & 15;

    // XCD-aware decode: WG i lands on XCD i%8; each XCD owns 4 (b,h) -> K/V set = 4 MB = L2.
    const int i  = blockIdx.x;             // grid = 512 -> 2 WGs/CU
    const int bh = (i & 7) * 4 + ((i >> 3) & 3);
    const int qb = i >> 5;
    const int b  = bh >> 4;
    const int h  = bh & 15;
    const int q0 = qb * BM;

    const int rowStride = H * E;  // 1024 floats
    const size_t qbase = ((size_t)b * L) * rowStride + h * E;
    const size_t kbase = ((size_t)b * S) * rowStride + h * E;

    const float cS = 0.125f * 1.44269504089f;  // scale*log2(e); fixed-shift exp2 softmax

    // ---- Q fragments for 2 q-groups, prescaled (B-operand: n=q=lq, k=e=ks*32+quad*8+j) ----
    half8 qf[2][2];
    #pragma unroll
    for (int g = 0; g < 2; ++g) {
        const float* qp = Qg + qbase + (size_t)(q0 + wave*32 + g*16 + lq) * rowStride + quad*8;
        #pragma unroll
        for (int ks = 0; ks < 2; ++ks)
            #pragma unroll
            for (int j = 0; j < 8; ++j)
                qf[g][ks][j] = (_Float16)(qp[ks*32 + j] * cS);
    }

    const float* mrow0 = Mg + (size_t)(q0 + wave*32 + lq) * S;  // g offset: +16*S

    float lsum[2] = {0.f, 0.f};
    f32x4 oacc[2][4];
    #pragma unroll
    for (int g = 0; g < 2; ++g)
        #pragma unroll
        for (int dt = 0; dt < 4; ++dt) oacc[g][dt] = (f32x4){0.f, 0.f, 0.f, 0.f};

    // staging decompositions (256 threads stage the 64x64 K and V tiles)
    const int db = tid & 15;
    const int sb = tid >> 4;
    const float* vbase = Vg + kbase + (size_t)(sb*4) * rowStride + db*4;
    const float* krow  = Kg + kbase + (size_t)(tid >> 4) * rowStride + (tid & 15)*4;
    const int voff = (((sb >> 1) ^ (db >> 1)) << 3) + ((sb & 1) << 2);

    // staging pipeline regs: tile t+1 lives here while tile t computes
    float4 kreg[4], vreg[4], mA[2][4], mB[2][4];

    // ---- prologue: load + stage tile 0 into buf0, prefetch mask tile 0 ----
    #pragma unroll
    for (int ii = 0; ii < 4; ++ii)
        kreg[ii] = *(const float4*)(krow + (size_t)(ii*16) * rowStride);
    #pragma unroll
    for (int j = 0; j < 4; ++j)
        vreg[j] = *(const float4*)(vbase + (size_t)j * rowStride);
    #pragma unroll
    for (int g = 0; g < 2; ++g)
        #pragma unroll
        for (int nt = 0; nt < 4; ++nt)
            mA[g][nt] = *(const float4*)(mrow0 + (size_t)g*16*S + nt*16 + quad*4);

    #pragma unroll
    for (int ii = 0; ii < 4; ++ii) {
        half4 hk = {(_Float16)kreg[ii].x, (_Float16)kreg[ii].y,
                    (_Float16)kreg[ii].z, (_Float16)kreg[ii].w};
        *(half4*)&sK[0][(tid >> 4) + ii*16][(tid & 15)*4] = hk;
    }
    #pragma unroll
    for (int j = 0; j < 4; ++j) {
        half4 hv = { (_Float16)((&vreg[0].x)[j]), (_Float16)((&vreg[1].x)[j]),
                     (_Float16)((&vreg[2].x)[j]), (_Float16)((&vreg[3].x)[j]) };
        *(half4*)&sV[0][db*4 + j][voff] = hv;
    }
    __syncthreads();

    // NTI = 32 (even): two steps per loop iteration with compile-time buffers.
    for (int tt = 0; tt < NTI; tt += 2) {
        TILE_STEP(0, mA, mB, tt)
        TILE_STEP(1, mB, mA, tt + 1)
    }

    // ---- epilogue per q-group: l reduction across quads, O /= l, store fp32 ----
    #pragma unroll
    for (int g = 0; g < 2; ++g) {
        float l = lsum[g];
        l += __shfl_xor(l, 16);
        l += __shfl_xor(l, 32);
        #pragma unroll
        for (int r = 0; r < 4; ++r) {
            float l_bc = __shfl(l, quad*4 + r, 16);
            float inv = 1.f / l_bc;
            float* orow = Og + qbase + (size_t)(q0 + wave*32 + g*16 + quad*4 + r) * rowStride;
            #pragma unroll
            for (int dt = 0; dt < 4; ++dt)
                orow[dt*16 + lq] = oacc[g][dt][r] * inv;
        }
    }
}

extern "C" void kernel_launch(void* const* d_in, const int* in_sizes, int n_in,
                              void* d_out, int out_size, void* d_ws, size_t ws_size,
                              hipStream_t stream) {
    const float* Qg = (const float*)d_in[0];
    const float* Kg = (const float*)d_in[1];
    const float* Vg = (const float*)d_in[2];
    const float* Mg = (const float*)d_in[3];
    float* Og = (float*)d_out;
    dim3 grid((L / BM) * B * H);   // 512 WGs = exactly 2 per CU
    fa_kernel<<<grid, 256, 0, stream>>>(Qg, Kg, Vg, Mg, Og);
}